// Round 1
// baseline (106.115 us; speedup 1.0000x reference)
//
#include <hip/hip_runtime.h>

// N_RNA=20000, N_PROT=5000, D=128, C=4, E=500000
#define DIM 128
#define NCLS 4

typedef _Float16 f16x4 __attribute__((ext_vector_type(4)));
typedef _Float16 f16x8 __attribute__((ext_vector_type(8)));
typedef float    f32x4 __attribute__((ext_vector_type(4)));

// ---------- merged fp32 -> fp16 conversion (both tables, one launch) ----------
__global__ __launch_bounds__(256) void cvt_both_kernel(
    const float* __restrict__ s1, _Float16* __restrict__ d1, int n1,
    const float* __restrict__ s2, _Float16* __restrict__ d2, int n2)
{
    // n1, n2 are multiples of 8, so an 8-group never straddles the boundary.
    const int total = n1 + n2;
    int i = (blockIdx.x * blockDim.x + threadIdx.x) * 8;
    const int stride = gridDim.x * blockDim.x * 8;
    for (; i < total; i += stride) {
        const float* s; _Float16* d; int j;
        if (i < n1) { s = s1; d = d1; j = i; }
        else        { s = s2; d = d2; j = i - n1; }
        const float4 a = *(const float4*)(s + j);
        const float4 b = *(const float4*)(s + j + 4);
        f16x8 o;
        o[0] = (_Float16)a.x; o[1] = (_Float16)a.y;
        o[2] = (_Float16)a.z; o[3] = (_Float16)a.w;
        o[4] = (_Float16)b.x; o[5] = (_Float16)b.y;
        o[6] = (_Float16)b.z; o[7] = (_Float16)b.w;
        *(f16x8*)(d + j) = o;
    }
}

// ---------- MFMA decoder ----------
// out[e, 0:4] = relu( (r[e] .* p[e]) @ WF ), WF[d, c] = sum_cc wrel[cc,d]*wcls[cc*4+c]
//
// One v_mfma_f32_16x16x32_f16 computes 16 edges x 4 classes x K=32; four chained
// MFMAs cover D=128. Operand mapping (16x16x32, verified C/D layout col=lane&15,
// row=(lane>>4)*4+reg):
//   A (first arg)  = WF^T: lane holds row m=lane&15 (class, rows 4..15 zeroed),
//                    k = (lane>>4)*8 + j   -> 8 f16 from wf_lds[m][...]
//   B (second arg) = q:    lane holds col n=lane&15 (edge),
//                    k = (lane>>4)*8 + j   -> 8 f16 of gathered row, one dwordx4
//   D: lanes 0..15 hold all 4 classes of edge (e0+lane) in regs 0..3 -> float4 store.
// ILP2: two independent 16-edge groups per wave per iteration = 16 dwordx4 in flight.
__global__ __launch_bounds__(256, 4) void decoder_mfma_kernel(
    const _Float16* __restrict__ rna,   // [N_RNA, D] f16
    const _Float16* __restrict__ prot,  // [N_PROT, D] f16
    const int*   __restrict__ ridx,
    const int*   __restrict__ pidx,
    const float* __restrict__ wrel,
    const float* __restrict__ wcls,
    float*       __restrict__ out,
    int nEdges)                          // requires nEdges % 32 == 0
{
    // ---- build fused f16 weights in LDS: wf_lds[c][d] = sum_cc wrel[cc,d]*wcls[cc,c]
    __shared__ _Float16 wf_lds[NCLS][DIM];
    {
        const int t = threadIdx.x;
        if (t < DIM) {
            const float w0 = wrel[0 * DIM + t];
            const float w1 = wrel[1 * DIM + t];
            const float w2 = wrel[2 * DIM + t];
            const float w3 = wrel[3 * DIM + t];
#pragma unroll
            for (int c = 0; c < NCLS; ++c) {
                wf_lds[c][t] = (_Float16)(w0 * wcls[0 * 4 + c] + w1 * wcls[1 * 4 + c] +
                                          w2 * wcls[2 * 4 + c] + w3 * wcls[3 * 4 + c]);
            }
        }
    }
    __syncthreads();

    const int lane = threadIdx.x & 63;
    const int l16  = lane & 15;   // edge-in-group (B) / class row (A)
    const int kg   = lane >> 4;   // k-subgroup 0..3 (8 elems each)

    // A fragments (constant over the whole kernel), rows >= NCLS are zero.
    f16x8 awf[4];
    const f16x8 fzero = {};
#pragma unroll
    for (int f = 0; f < 4; ++f)
        awf[f] = (l16 < NCLS) ? *(const f16x8*)(&wf_lds[l16][f * 32 + kg * 8]) : fzero;

    const int wid   = (int)((blockIdx.x * blockDim.x + threadIdx.x) >> 6);
    const int nw    = (int)((gridDim.x * blockDim.x) >> 6);
    const int npair = nEdges >> 5;          // 32 edges per iteration

    const size_t khi  = (size_t)kg * 16;    // byte offset of k-subgroup within 256B row
    const char* rbase = (const char*)rna  + khi;
    const char* pbase = (const char*)prot + khi;

    int pr = wid;
    if (pr >= npair) return;

    int e0  = pr * 32;
    int riA = ridx[e0 + l16],      piA = pidx[e0 + l16];
    int riB = ridx[e0 + 16 + l16], piB = pidx[e0 + 16 + l16];

    for (;;) {
        // ---- issue all 16 gather dwordx4 loads back-to-back ----
        const char* ra = rbase + ((size_t)riA << 8);
        const char* pa = pbase + ((size_t)piA << 8);
        const char* rb = rbase + ((size_t)riB << 8);
        const char* pb = pbase + ((size_t)piB << 8);
        f16x8 rAv[4], pAv[4], rBv[4], pBv[4];
#pragma unroll
        for (int f = 0; f < 4; ++f) rAv[f] = *(const f16x8*)(ra + f * 64);
#pragma unroll
        for (int f = 0; f < 4; ++f) pAv[f] = *(const f16x8*)(pa + f * 64);
#pragma unroll
        for (int f = 0; f < 4; ++f) rBv[f] = *(const f16x8*)(rb + f * 64);
#pragma unroll
        for (int f = 0; f < 4; ++f) pBv[f] = *(const f16x8*)(pb + f * 64);

        // ---- prefetch next iteration's indices while gathers are in flight ----
        const int  prn  = pr + nw;
        const bool more = prn < npair;
        if (more) {
            const int en = prn * 32;
            riA = ridx[en + l16];      piA = pidx[en + l16];
            riB = ridx[en + 16 + l16]; piB = pidx[en + 16 + l16];
        }

        // ---- q = r .* p (packed f16), reduce via MFMA ----
        f32x4 accA = {}, accB = {};
#pragma unroll
        for (int f = 0; f < 4; ++f) {
            const f16x8 q = rAv[f] * pAv[f];
            accA = __builtin_amdgcn_mfma_f32_16x16x32_f16(awf[f], q, accA, 0, 0, 0);
        }
#pragma unroll
        for (int f = 0; f < 4; ++f) {
            const f16x8 q = rBv[f] * pBv[f];
            accB = __builtin_amdgcn_mfma_f32_16x16x32_f16(awf[f], q, accB, 0, 0, 0);
        }

        // ---- relu + contiguous float4 store (lanes 0..15 hold valid class rows) ----
        if (lane < 16) {
            f32x4 oA, oB;
#pragma unroll
            for (int j = 0; j < 4; ++j) {
                oA[j] = fmaxf(accA[j], 0.0f);
                oB[j] = fmaxf(accB[j], 0.0f);
            }
            *(f32x4*)(out + (size_t)(e0 + l16) * NCLS)        = oA;
            *(f32x4*)(out + (size_t)(e0 + 16 + l16) * NCLS)   = oB;
        }

        if (!more) break;
        pr = prn;
        e0 = prn * 32;
    }
}

// ---------- fp32 fallback (handles any shape / tiny workspace) ----------
__device__ __forceinline__ float reduce4_f32(float b0, float b1, float b2, float b3, int lane)
{
    const bool lo1 = (lane & 1) == 0;
    float k0 = lo1 ? b0 : b2, s0 = lo1 ? b2 : b0;
    float k1 = lo1 ? b1 : b3, s1 = lo1 ? b3 : b1;
    float v0 = k0 + __shfl_xor(s0, 1, 32);
    float v1 = k1 + __shfl_xor(s1, 1, 32);
    const bool lo2 = (lane & 2) == 0;
    float k = lo2 ? v0 : v1, s = lo2 ? v1 : v0;
    float v = k + __shfl_xor(s, 2, 32);
    v += __shfl_xor(v, 4, 32);
    v += __shfl_xor(v, 8, 32);
    v += __shfl_xor(v, 16, 32);
    return v;
}

__global__ __launch_bounds__(256) void decoder_f32_kernel(
    const float* __restrict__ rna, const float* __restrict__ prot,
    const int* __restrict__ ridx, const int* __restrict__ pidx,
    const float* __restrict__ wrel, const float* __restrict__ wcls,
    float* __restrict__ out, int nEdges)
{
    const int lane32 = threadIdx.x & 31;
    const int hw     = (blockIdx.x * blockDim.x + threadIdx.x) >> 5;
    const int nhw    = (gridDim.x * blockDim.x) >> 5;
    const float4 w0 = *(const float4*)(wrel + 0 * DIM + lane32 * 4);
    const float4 w1 = *(const float4*)(wrel + 1 * DIM + lane32 * 4);
    const float4 w2 = *(const float4*)(wrel + 2 * DIM + lane32 * 4);
    const float4 w3 = *(const float4*)(wrel + 3 * DIM + lane32 * 4);
    float wc[16];
#pragma unroll
    for (int i = 0; i < 16; ++i) wc[i] = wcls[i];
    float4 wf[4];
#pragma unroll
    for (int j = 0; j < 4; ++j) {
        wf[j].x = wc[j] * w0.x + wc[4 + j] * w1.x + wc[8 + j] * w2.x + wc[12 + j] * w3.x;
        wf[j].y = wc[j] * w0.y + wc[4 + j] * w1.y + wc[8 + j] * w2.y + wc[12 + j] * w3.y;
        wf[j].z = wc[j] * w0.z + wc[4 + j] * w1.z + wc[8 + j] * w2.z + wc[12 + j] * w3.z;
        wf[j].w = wc[j] * w0.w + wc[4 + j] * w1.w + wc[8 + j] * w2.w + wc[12 + j] * w3.w;
    }
    const int cls   = ((lane32 & 1) << 1) | ((lane32 >> 1) & 1);
    const int lelem = lane32 * 4;
    for (int e = hw; e < nEdges; e += nhw) {
        const float4 r = *(const float4*)(rna  + (size_t)ridx[e] * DIM + lelem);
        const float4 p = *(const float4*)(prot + (size_t)pidx[e] * DIM + lelem);
        float qx = r.x * p.x, qy = r.y * p.y, qz = r.z * p.z, qw = r.w * p.w;
        float b0 = qx * wf[0].x + qy * wf[0].y + qz * wf[0].z + qw * wf[0].w;
        float b1 = qx * wf[1].x + qy * wf[1].y + qz * wf[1].z + qw * wf[1].w;
        float b2 = qx * wf[2].x + qy * wf[2].y + qz * wf[2].z + qw * wf[2].w;
        float b3 = qx * wf[3].x + qy * wf[3].y + qz * wf[3].z + qw * wf[3].w;
        const float v = reduce4_f32(b0, b1, b2, b3, lane32);
        if (lane32 < 4) out[(size_t)e * NCLS + cls] = fmaxf(v, 0.0f);
    }
}

extern "C" void kernel_launch(void* const* d_in, const int* in_sizes, int n_in,
                              void* d_out, int out_size, void* d_ws, size_t ws_size,
                              hipStream_t stream) {
    const float* rna  = (const float*)d_in[0];
    const float* prot = (const float*)d_in[1];
    const int*   ridx = (const int*)d_in[2];
    const int*   pidx = (const int*)d_in[3];
    const float* wrel = (const float*)d_in[4];
    const float* wcls = (const float*)d_in[5];
    float*       out  = (float*)d_out;

    const int nRnaElems  = in_sizes[0];   // 20000*128
    const int nProtElems = in_sizes[1];   // 5000*128
    const int nEdges     = in_sizes[2];   // 500000

    const size_t rnaBytes  = (size_t)nRnaElems * 2;
    const size_t needBytes = rnaBytes + (size_t)nProtElems * 2;

    if (ws_size >= needBytes && (nEdges % 32) == 0 && nEdges >= 32 &&
        (nRnaElems % 8) == 0 && (nProtElems % 8) == 0) {
        _Float16* rnaH  = (_Float16*)d_ws;
        _Float16* protH = (_Float16*)((char*)d_ws + rnaBytes);

        const int totalElems = nRnaElems + nProtElems;
        const int cvtBlocks  = (totalElems / 8 + 255) / 256;
        hipLaunchKernelGGL(cvt_both_kernel, dim3(cvtBlocks), dim3(256), 0, stream,
                           rna, rnaH, nRnaElems, prot, protH, nProtElems);

        // 1024 blocks = 4 blocks/CU resident at __launch_bounds__(256,4);
        // 4096 waves x ~3.8 iterations of 32 edges, 16 dwordx4 in flight each.
        hipLaunchKernelGGL(decoder_mfma_kernel, dim3(1024), dim3(256), 0, stream,
                           rnaH, protH, ridx, pidx, wrel, wcls, out, nEdges);
    } else {
        hipLaunchKernelGGL(decoder_f32_kernel, dim3(8192), dim3(256), 0, stream,
                           rna, prot, ridx, pidx, wrel, wcls, out, nEdges);
    }
}